// Round 7
// baseline (6237.786 us; speedup 1.0000x reference)
//
#include <hip/hip_runtime.h>
#include <math.h>

typedef __attribute__((ext_vector_type(8))) __bf16 bf16x8;
typedef __attribute__((ext_vector_type(4))) float f32x4;

constexpr int H = 1024, T = 64, NB = 256, TWOH = 2048, THREEH = 3072;
constexpr long long OFF_Q  = 33554432LL;
constexpr long long OFF_HX = 67108864LL;
constexpr int LA = 6;      // filler lookahead (ring of 8 slices)

// Wbf row offsets (rows of 1024 bf16, byte stride 2048)
constexpr int R_PWH = 0, R_PWQ = 2048, R_QWF = 4096, R_QWC = 6144,
              R_FWIH = 8192, R_FWHH = 11264, R_HWIH = 14336, R_HWHH = 17408;

#define LD4(p) (*reinterpret_cast<const float4*>(p))

__device__ __forceinline__ float sigf(float x) { return 1.0f / (1.0f + expf(-x)); }

__device__ __forceinline__ void gload16(const void* g, void* l) {
    __builtin_amdgcn_global_load_lds(
        (const __attribute__((address_space(1))) uint32_t*)g,
        (__attribute__((address_space(3))) uint32_t*)l, 16, 0, 0);
}

__device__ __forceinline__ void st_bf_swz(__bf16* base, int n, int k, float v) {
    base[(size_t)n * 1024 + (((k >> 3) ^ (n & 7)) << 3) + (k & 7)] = (__bf16)v;
}

#define FRAGOFF(rloc, gl) (((rloc) << 7) + ((((gl)) ^ ((rloc) & 7)) << 4))

// stage RT rows x 64 k from pre-swizzled global (row stride 2048B)
template<int RT>
__device__ __forceinline__ void stage_tile(const char* g, char* l, int kb, int tid) {
    #pragma unroll
    for (int i = 0; i < RT / 32; ++i) {
        const int L = i * 4096 + tid * 16;
        gload16(g + (size_t)(L >> 7) * 2048 + (size_t)kb * 128 + (L & 127), l + L);
    }
}

// ---------------------------------------------------------------- 64x128 GEMM core
__device__ __forceinline__ void mm128(
    int tid, char* sA, char* sB,
    const char* A0, const char* B0, int n0,
    const char* A1, const char* B1, int n1,
    f32x4 (&acc)[2][4])
{
    const int lane = tid & 63, w = tid >> 6;
    const int l15 = lane & 15, lg = lane >> 4;
    const int wr = w >> 1, wc = w & 1;
    const int nit = n0 + n1;
    int aoff[2][2], boff[4][2];
    #pragma unroll
    for (int fr = 0; fr < 2; ++fr)
        #pragma unroll
        for (int kk = 0; kk < 2; ++kk)
            aoff[fr][kk] = FRAGOFF(wr * 32 + fr * 16 + l15, kk * 4 + lg);
    #pragma unroll
    for (int fc = 0; fc < 4; ++fc)
        #pragma unroll
        for (int kk = 0; kk < 2; ++kk)
            boff[fc][kk] = FRAGOFF(wc * 64 + fc * 16 + l15, kk * 4 + lg);

    stage_tile<64>(A0, sA, 0, tid);
    stage_tile<128>(B0, sB, 0, tid);
    for (int kb = 0; kb < nit; ++kb) {
        const int kn = kb + 1;
        if (kn < nit) {
            const char* An = (kn < n0) ? A0 : A1;
            const char* Bn = (kn < n0) ? B0 : B1;
            const int kl = (kn < n0) ? kn : kn - n0;
            stage_tile<64>(An, sA + (kn & 1) * 8192, kl, tid);
            stage_tile<128>(Bn, sB + (kn & 1) * 16384, kl, tid);
            asm volatile("s_waitcnt vmcnt(6)" ::: "memory");
        } else {
            asm volatile("s_waitcnt vmcnt(0)" ::: "memory");
        }
        __builtin_amdgcn_s_barrier();
        __builtin_amdgcn_sched_barrier(0);
        char* Ab = sA + (kb & 1) * 8192;
        char* Bb = sB + (kb & 1) * 16384;
        bf16x8 af[2][2], bv[4][2];
        #pragma unroll
        for (int fr = 0; fr < 2; ++fr)
            #pragma unroll
            for (int kk = 0; kk < 2; ++kk)
                af[fr][kk] = *reinterpret_cast<const bf16x8*>(Ab + aoff[fr][kk]);
        #pragma unroll
        for (int fc = 0; fc < 4; ++fc)
            #pragma unroll
            for (int kk = 0; kk < 2; ++kk)
                bv[fc][kk] = *reinterpret_cast<const bf16x8*>(Bb + boff[fc][kk]);
        __builtin_amdgcn_s_setprio(1);
        #pragma unroll
        for (int kk = 0; kk < 2; ++kk)
            #pragma unroll
            for (int fr = 0; fr < 2; ++fr)
                #pragma unroll
                for (int fc = 0; fc < 4; ++fc)
                    acc[fr][fc] = __builtin_amdgcn_mfma_f32_16x16x32_bf16(
                        af[fr][kk], bv[fc][kk], acc[fr][fc], 0, 0, 0);
        __builtin_amdgcn_s_setprio(0);
        __builtin_amdgcn_s_barrier();
        __builtin_amdgcn_sched_barrier(0);
    }
}

// ---------------------------------------------------------------- 64x64 3-gate multi-seg core
// Segments (up to 3): A from As, B (3 gate tiles) from Bs. n-gate MFMA routes to
// aNh if bit seg of nhMask set, else aNi. r/z gates always accumulate into aR/aZ.
__device__ __forceinline__ void mm64g(
    int tid, char* sA, char* sB,
    const char* A0, const char* B0,
    const char* A1, const char* B1,
    const char* A2, const char* B2,
    int nseg, int nhMask,
    f32x4 (&aR)[2][2], f32x4 (&aZ)[2][2], f32x4 (&aNi)[2][2], f32x4 (&aNh)[2][2])
{
    const int lane = tid & 63, w = tid >> 6;
    const int l15 = lane & 15, lg = lane >> 4;
    const int wr = w >> 1, wc = w & 1;
    const int nit = nseg * 16;
    int aoff[2][2], boff[2][2];
    #pragma unroll
    for (int fr = 0; fr < 2; ++fr)
        #pragma unroll
        for (int kk = 0; kk < 2; ++kk)
            aoff[fr][kk] = FRAGOFF(wr * 32 + fr * 16 + l15, kk * 4 + lg);
    #pragma unroll
    for (int fc = 0; fc < 2; ++fc)
        #pragma unroll
        for (int kk = 0; kk < 2; ++kk)
            boff[fc][kk] = FRAGOFF(wc * 32 + fc * 16 + l15, kk * 4 + lg);

    auto stg = [&](int buf, int kb) {
        const int seg = kb >> 4, kl = kb & 15;
        const char* Ag = (seg == 0) ? A0 : ((seg == 1) ? A1 : A2);
        const char* Bg = (seg == 0) ? B0 : ((seg == 1) ? B1 : B2);
        stage_tile<64>(Ag, sA + buf * 8192, kl, tid);
        #pragma unroll
        for (int g = 0; g < 3; ++g)
            stage_tile<64>(Bg + (size_t)g * 2097152, sB + buf * 24576 + g * 8192, kl, tid);
    };
    stg(0, 0);
    for (int kb = 0; kb < nit; ++kb) {
        if (kb + 1 < nit) {
            stg((kb + 1) & 1, kb + 1);
            asm volatile("s_waitcnt vmcnt(8)" ::: "memory");
        } else {
            asm volatile("s_waitcnt vmcnt(0)" ::: "memory");
        }
        __builtin_amdgcn_s_barrier();
        __builtin_amdgcn_sched_barrier(0);
        char* Ab = sA + (kb & 1) * 8192;
        char* Bb = sB + (kb & 1) * 24576;
        bf16x8 af[2][2];
        #pragma unroll
        for (int fr = 0; fr < 2; ++fr)
            #pragma unroll
            for (int kk = 0; kk < 2; ++kk)
                af[fr][kk] = *reinterpret_cast<const bf16x8*>(Ab + aoff[fr][kk]);
        bf16x8 bvr[2][2], bvz[2][2], bvn[2][2];
        #pragma unroll
        for (int fc = 0; fc < 2; ++fc)
            #pragma unroll
            for (int kk = 0; kk < 2; ++kk) {
                bvr[fc][kk] = *reinterpret_cast<const bf16x8*>(Bb + boff[fc][kk]);
                bvz[fc][kk] = *reinterpret_cast<const bf16x8*>(Bb + 8192 + boff[fc][kk]);
                bvn[fc][kk] = *reinterpret_cast<const bf16x8*>(Bb + 16384 + boff[fc][kk]);
            }
        const bool toNh = (nhMask >> (kb >> 4)) & 1;
        __builtin_amdgcn_s_setprio(1);
        #pragma unroll
        for (int kk = 0; kk < 2; ++kk)
            #pragma unroll
            for (int fr = 0; fr < 2; ++fr)
                #pragma unroll
                for (int fc = 0; fc < 2; ++fc) {
                    aR[fr][fc] = __builtin_amdgcn_mfma_f32_16x16x32_bf16(
                        af[fr][kk], bvr[fc][kk], aR[fr][fc], 0, 0, 0);
                    aZ[fr][fc] = __builtin_amdgcn_mfma_f32_16x16x32_bf16(
                        af[fr][kk], bvz[fc][kk], aZ[fr][fc], 0, 0, 0);
                }
        if (toNh) {
            #pragma unroll
            for (int kk = 0; kk < 2; ++kk)
                #pragma unroll
                for (int fr = 0; fr < 2; ++fr)
                    #pragma unroll
                    for (int fc = 0; fc < 2; ++fc)
                        aNh[fr][fc] = __builtin_amdgcn_mfma_f32_16x16x32_bf16(
                            af[fr][kk], bvn[fc][kk], aNh[fr][fc], 0, 0, 0);
        } else {
            #pragma unroll
            for (int kk = 0; kk < 2; ++kk)
                #pragma unroll
                for (int fr = 0; fr < 2; ++fr)
                    #pragma unroll
                    for (int fc = 0; fc < 2; ++fc)
                        aNi[fr][fc] = __builtin_amdgcn_mfma_f32_16x16x32_bf16(
                            af[fr][kk], bvn[fc][kk], aNi[fr][fc], 0, 0, 0);
        }
        __builtin_amdgcn_s_setprio(0);
        __builtin_amdgcn_s_barrier();
        __builtin_amdgcn_sched_barrier(0);
    }
}

// ---------------------------------------------------------------- filler bodies
__device__ __forceinline__ void do_xq(int slice, int i, int tid, char* sA, char* sB,
    const char* cbfB, const char* Wb, const float* act, const float* qW, float* out)
{
    const int lane = tid & 63, w = tid >> 6;
    const int l15 = lane & 15, lg = lane >> 4;
    const int wr = w >> 1, wc = w & 1;
    const int row0 = (i >> 4) * 64, col0 = (i & 15) * 128;
    const size_t grow0 = (size_t)slice * NB + row0;
    f32x4 acc[2][4] = {};
    mm128(tid, sA, sB, cbfB + grow0 * 2048, Wb + (size_t)(R_QWC + col0) * 2048, 16,
          nullptr, nullptr, 0, acc);
    #pragma unroll
    for (int fc = 0; fc < 4; ++fc) {
        const int gc = col0 + wc * 64 + fc * 16 + l15;
        const float* wp = qW + (size_t)gc * 2056 + 2048;
        float4 x0 = LD4(wp), x1 = LD4(wp + 4);
        #pragma unroll
        for (int fr = 0; fr < 2; ++fr)
            #pragma unroll
            for (int j = 0; j < 4; ++j) {
                const size_t n = grow0 + wr * 32 + fr * 16 + lg * 4 + j;
                const float* ar = act + n * 8;
                float4 a0 = LD4(ar), a1 = LD4(ar + 4);
                float dot = a0.x * x0.x + a0.y * x0.y + a0.z * x0.z + a0.w * x0.w
                          + a1.x * x1.x + a1.y * x1.y + a1.z * x1.z + a1.w * x1.w;
                out[OFF_Q + n * TWOH + gc] = acc[fr][fc][j] + dot;
            }
    }
}

__device__ __forceinline__ void do_gf(int slice, int i, int tid, char* sA, char* sB,
    const char* cbfB, const char* Wb, __bf16* Gfb)
{
    const int lane = tid & 63, w = tid >> 6;
    const int l15 = lane & 15, lg = lane >> 4;
    const int wr = w >> 1, wc = w & 1;
    const int row0 = (i / 24) * 64, col0 = (i % 24) * 128;
    f32x4 acc[2][4] = {};
    mm128(tid, sA, sB, cbfB + ((size_t)slice * NB + row0) * 2048,
          Wb + (size_t)(R_FWIH + col0) * 2048, 16, nullptr, nullptr, 0, acc);
    __bf16* gdst = Gfb + (size_t)(slice & 7) * NB * THREEH;
    #pragma unroll
    for (int fc = 0; fc < 4; ++fc) {
        const int gc = col0 + wc * 64 + fc * 16 + l15;
        #pragma unroll
        for (int fr = 0; fr < 2; ++fr)
            #pragma unroll
            for (int j = 0; j < 4; ++j) {
                const int n = row0 + wr * 32 + fr * 16 + lg * 4 + j;
                gdst[(size_t)n * THREEH + gc] = (__bf16)acc[fr][fc][j];
            }
    }
}

// ---------------------------------------------------------------- prepass kernels
__global__ __launch_bounds__(256) void wcvt_k(
    const float* __restrict__ pW, const float* __restrict__ qW,
    const float* __restrict__ fWih, const float* __restrict__ fWhh,
    const float* __restrict__ hWih, const float* __restrict__ hWhh,
    __bf16* __restrict__ Wbf)
{
    const long i = (long)blockIdx.x * 256 + threadIdx.x;
    const int row = (int)(i >> 7);
    const int G   = (int)i & 127;
    const float* src; int stride; int koff = 0; int r;
    if (row < 2048)       { src = pW;   stride = 2056; koff = 0;    r = row; }
    else if (row < 4096)  { src = pW;   stride = 2056; koff = 1024; r = row - 2048; }
    else if (row < 6144)  { src = qW;   stride = 2056; koff = 0;    r = row - 4096; }
    else if (row < 8192)  { src = qW;   stride = 2056; koff = 1024; r = row - 6144; }
    else if (row < 11264) { src = fWih; stride = 1024; r = row - 8192; }
    else if (row < 14336) { src = fWhh; stride = 1024; r = row - 11264; }
    else if (row < 17408) { src = hWih; stride = 1024; r = row - 14336; }
    else                  { src = hWhh; stride = 1024; r = row - 17408; }
    const float* p = src + (long)r * stride + koff + G * 8;
    float4 a = LD4(p), b = LD4(p + 4);
    bf16x8 v;
    v[0] = (__bf16)a.x; v[1] = (__bf16)a.y; v[2] = (__bf16)a.z; v[3] = (__bf16)a.w;
    v[4] = (__bf16)b.x; v[5] = (__bf16)b.y; v[6] = (__bf16)b.z; v[7] = (__bf16)b.w;
    *reinterpret_cast<bf16x8*>(Wbf + (size_t)row * 1024 + ((G ^ (row & 7)) << 3)) = v;
}

__global__ __launch_bounds__(256) void ccvt_k(const float* __restrict__ c,
                                              __bf16* __restrict__ cbf) {
    const long i = (long)blockIdx.x * 256 + threadIdx.x;
    const int row = (int)(i >> 7);
    const int G   = (int)i & 127;
    const float* p = c + (size_t)row * 1024 + G * 8;
    float4 a = LD4(p), b = LD4(p + 4);
    bf16x8 v;
    v[0] = (__bf16)a.x; v[1] = (__bf16)a.y; v[2] = (__bf16)a.z; v[3] = (__bf16)a.w;
    v[4] = (__bf16)b.x; v[5] = (__bf16)b.y; v[6] = (__bf16)b.z; v[7] = (__bf16)b.w;
    *reinterpret_cast<bf16x8*>(cbf + (size_t)row * 1024 + ((G ^ (row & 7)) << 3)) = v;
}

// transpose pW[:1024, :2048] -> pWT (2048 rows x 1024 k, bf16 swizzled)
__global__ __launch_bounds__(256) void pwt_k(const float* __restrict__ pW,
                                             __bf16* __restrict__ pWT) {
    __shared__ float lds[64][65];
    const int t = threadIdx.x;
    const int i0 = blockIdx.y * 64, j0 = blockIdx.x * 64;
    const int ir = t >> 4, jc = (t & 15) * 4;
    #pragma unroll
    for (int rr = 0; rr < 4; ++rr) {
        const int il = rr * 16 + ir;
        float4 v = LD4(pW + (size_t)(i0 + il) * 2056 + j0 + jc);
        lds[jc + 0][il] = v.x; lds[jc + 1][il] = v.y;
        lds[jc + 2][il] = v.z; lds[jc + 3][il] = v.w;
    }
    __syncthreads();
    #pragma unroll
    for (int ww = 0; ww < 2; ++ww) {
        const int jl = ww * 32 + (t >> 3);
        const int g8 = t & 7;
        bf16x8 v;
        #pragma unroll
        for (int u = 0; u < 8; ++u) v[u] = (__bf16)lds[jl][g8 * 8 + u];
        const int j = j0 + jl;
        const int G = (i0 >> 3) + g8;
        *reinterpret_cast<bf16x8*>(pWT + (size_t)j * 1024 + ((G ^ (j & 7)) << 3)) = v;
    }
}

// composite GEMM: C(g,j) = sum_i hWih(g,i)*pW(i,j) -> Ch (j<1024), Cq (j>=1024)
__global__ __launch_bounds__(256) void comp_k(const char* __restrict__ Wb,
                                              const char* __restrict__ pWTb,
                                              __bf16* __restrict__ Ch,
                                              __bf16* __restrict__ Cq) {
    __shared__ char smem[49152];
    const int tid = threadIdx.x;
    const int lane = tid & 63, w = tid >> 6;
    const int l15 = lane & 15, lg = lane >> 4;
    const int wr = w >> 1, wc = w & 1;
    const int row0 = (blockIdx.x >> 4) * 64;
    const int col0 = (blockIdx.x & 15) * 128;
    f32x4 acc[2][4] = {};
    mm128(tid, smem, smem + 16384,
          Wb + (size_t)(R_HWIH + row0) * 2048, pWTb + (size_t)col0 * 2048, 16,
          nullptr, nullptr, 0, acc);
    #pragma unroll
    for (int fc = 0; fc < 4; ++fc) {
        const int j = col0 + wc * 64 + fc * 16 + l15;
        #pragma unroll
        for (int fr = 0; fr < 2; ++fr)
            #pragma unroll
            for (int jj = 0; jj < 4; ++jj) {
                const int g = row0 + wr * 32 + fr * 16 + lg * 4 + jj;
                const float v = acc[fr][fc][jj];
                if (j < 1024) st_bf_swz(Ch, g, j, v);
                else          st_bf_swz(Cq, g, j - 1024, v);
            }
    }
}

// Ca(g,u) = sum_i hWih(g,i)*pW(i,2048+u); cb(g) = sum_i hWih(g,i)*pb(i)
__global__ __launch_bounds__(256) void ca_k(const float* __restrict__ hWih,
                                            const float* __restrict__ pW,
                                            const float* __restrict__ pb,
                                            float* __restrict__ Ca,
                                            float* __restrict__ cbv) {
    const int g = blockIdx.x * 4 + (threadIdx.x >> 6);
    const int l = threadIdx.x & 63;
    float s[9] = {};
    for (int it = 0; it < 16; ++it) {
        const int i = l + it * 64;
        const float hw = hWih[(size_t)g * 1024 + i];
        const float* pr = pW + (size_t)i * 2056 + 2048;
        float4 x0 = LD4(pr), x1 = LD4(pr + 4);
        s[0] += hw * x0.x; s[1] += hw * x0.y; s[2] += hw * x0.z; s[3] += hw * x0.w;
        s[4] += hw * x1.x; s[5] += hw * x1.y; s[6] += hw * x1.z; s[7] += hw * x1.w;
        s[8] += hw * pb[i];
    }
    #pragma unroll
    for (int off = 32; off >= 1; off >>= 1)
        #pragma unroll
        for (int u = 0; u < 9; ++u) s[u] += __shfl_down(s[u], off);
    if (l == 0) {
        #pragma unroll
        for (int u = 0; u < 8; ++u) Ca[(size_t)g * 8 + u] = s[u];
        cbv[g] = s[8];
    }
}

__global__ __launch_bounds__(256) void init2_k(
    const float* __restrict__ hxs, const float* __restrict__ masks,
    float* __restrict__ fst0, float* __restrict__ hst0,
    __bf16* __restrict__ fbm0, __bf16* __restrict__ hbm0, __bf16* __restrict__ qmub0)
{
    const int idx = blockIdx.x * 256 + threadIdx.x;
    const int arr = idx >> 15;
    const int g   = idx & 32767;
    const int n   = g >> 7;
    const int G   = g & 127;
    const float m0 = masks[n];
    const float* p = hxs + (size_t)n * THREEH + arr * 1024 + G * 8;
    float4 a = LD4(p), b = LD4(p + 4);
    __bf16* dstB = arr == 0 ? fbm0 : (arr == 1 ? hbm0 : qmub0);
    bf16x8 v;
    v[0] = (__bf16)(a.x * m0); v[1] = (__bf16)(a.y * m0);
    v[2] = (__bf16)(a.z * m0); v[3] = (__bf16)(a.w * m0);
    v[4] = (__bf16)(b.x * m0); v[5] = (__bf16)(b.y * m0);
    v[6] = (__bf16)(b.z * m0); v[7] = (__bf16)(b.w * m0);
    *reinterpret_cast<bf16x8*>(dstB + (size_t)n * 1024 + ((G ^ (n & 7)) << 3)) = v;
    if (arr < 2) {
        float* dstF = arr == 0 ? fst0 : hst0;
        *reinterpret_cast<float4*>(dstF + (size_t)n * 1024 + G * 8) = a;
        *reinterpret_cast<float4*>(dstF + (size_t)n * 1024 + G * 8 + 4) = b;
    }
}

__global__ __launch_bounds__(256) void pre_k(
    const char* __restrict__ cbfB, const char* __restrict__ Wb,
    const float* __restrict__ act, const float* __restrict__ qW,
    __bf16* __restrict__ Gfb, float* __restrict__ out)
{
    __shared__ char smem[49152];
    const int s = blockIdx.x / 160;
    const int i = blockIdx.x % 160;
    if (i < 64) do_xq(s, i, threadIdx.x, smem, smem + 16384, cbfB, Wb, act, qW, out);
    else        do_gf(s, i - 64, threadIdx.x, smem, smem + 16384, cbfB, Wb, Gfb);
}

// ---------------------------------------------------------------- fused per-step kernel
// [0,64) P | [64,128) Q | [128,192) h-GRU | [192,256) f-GRU | [256,416) fillers(t+LA)
__global__ __launch_bounds__(256) void step_k(
    int t, int hasFiller,
    const __bf16* __restrict__ hbm, const __bf16* __restrict__ qmub,
    __bf16* __restrict__ qmubN,
    const __bf16* __restrict__ fbm, const char* __restrict__ cbfB,
    const float* __restrict__ masks, const float* __restrict__ act,
    const float* __restrict__ pW, const float* __restrict__ pb,
    const float* __restrict__ qb, const float* __restrict__ qW,
    const char* __restrict__ Wb, const char* __restrict__ ChB,
    const char* __restrict__ CqB,
    const float* __restrict__ Ca, const float* __restrict__ cbv,
    const float* __restrict__ hstF, float* __restrict__ hstN, __bf16* __restrict__ hbmN,
    const float* __restrict__ fstF, float* __restrict__ fstN, __bf16* __restrict__ fbmN,
    const float* __restrict__ hbih, const float* __restrict__ hbhh,
    const float* __restrict__ fbih, const float* __restrict__ fbhh,
    __bf16* __restrict__ Gfb, float* __restrict__ out)
{
    __shared__ char smem[65536];
    char* sA = smem;
    char* sB = smem + 16384;
    const int tid = threadIdx.x;
    const int lane = tid & 63, w = tid >> 6;
    const int l15 = lane & 15, lg = lane >> 4;
    const int wr = w >> 1, wc = w & 1;
    const float* mrow = masks + (size_t)t * NB;
    const float* mn   = masks + (size_t)(t + 1 < T ? t + 1 : t) * NB;
    int b = blockIdx.x;

    if (b < 64) {           // ---- P
        const int row0 = (b >> 4) * 64, col0 = (b & 15) * 128;
        f32x4 acc[2][4] = {};
        mm128(tid, sA, sB,
              (const char*)hbm + (size_t)row0 * 2048, Wb + (size_t)(R_PWH + col0) * 2048, 16,
              (const char*)qmub + (size_t)row0 * 2048, Wb + (size_t)(R_PWQ + col0) * 2048, 16,
              acc);
        float* ob = out + (size_t)t * NB * TWOH;
        #pragma unroll
        for (int fc = 0; fc < 4; ++fc) {
            const int gc = col0 + wc * 64 + fc * 16 + l15;
            const float* wp = pW + (size_t)gc * 2056 + 2048;
            float4 x0 = LD4(wp), x1 = LD4(wp + 4);
            const float bb = pb[gc];
            #pragma unroll
            for (int fr = 0; fr < 2; ++fr)
                #pragma unroll
                for (int j = 0; j < 4; ++j) {
                    const int n = row0 + wr * 32 + fr * 16 + lg * 4 + j;
                    const float* ar = act + ((size_t)t * NB + n) * 8;
                    float4 a0 = LD4(ar), a1 = LD4(ar + 4);
                    float dot = a0.x * x0.x + a0.y * x0.y + a0.z * x0.z + a0.w * x0.w
                              + a1.x * x1.x + a1.y * x1.y + a1.z * x1.z + a1.w * x1.w;
                    ob[(size_t)n * TWOH + gc] = acc[fr][fc][j] + mrow[n] * dot + bb;
                }
        }
    } else if (b < 128) {   // ---- Q
        b -= 64;
        const int row0 = (b >> 4) * 64, col0 = (b & 15) * 128;
        f32x4 acc[2][4] = {};
        mm128(tid, sA, sB,
              (const char*)fbm + (size_t)row0 * 2048, Wb + (size_t)(R_QWF + col0) * 2048, 16,
              nullptr, nullptr, 0, acc);
        float* ob = out + OFF_Q + (size_t)t * NB * TWOH;
        #pragma unroll
        for (int fc = 0; fc < 4; ++fc) {
            const int gc = col0 + wc * 64 + fc * 16 + l15;
            const float bb = qb[gc];
            #pragma unroll
            for (int fr = 0; fr < 2; ++fr)
                #pragma unroll
                for (int j = 0; j < 4; ++j) {
                    const int n = row0 + wr * 32 + fr * 16 + lg * 4 + j;
                    const float xq = ob[(size_t)n * TWOH + gc];
                    float v = acc[fr][fc][j] + mrow[n] * xq + bb;
                    ob[(size_t)n * TWOH + gc] = v;
                    if (gc < 1024) st_bf_swz(qmubN, n, gc, v * mn[n]);
                }
        }
    } else if (b < 192) {   // ---- h-GRU (composite): segs {h x Ch, h x hWhh, qmu x Cq}
        const int i = b - 128;
        const int row0 = (i >> 4) * 64, col0 = (i & 15) * 64;
        f32x4 aR[2][2] = {}, aZ[2][2] = {}, aNi[2][2] = {}, aNh[2][2] = {};
        mm64g(tid, sA, sB,
              (const char*)hbm + (size_t)row0 * 2048, ChB + (size_t)col0 * 2048,
              (const char*)hbm + (size_t)row0 * 2048, Wb + (size_t)(R_HWHH + col0) * 2048,
              (const char*)qmub + (size_t)row0 * 2048, CqB + (size_t)col0 * 2048,
              3, 0b010, aR, aZ, aNi, aNh);
        #pragma unroll
        for (int fc = 0; fc < 2; ++fc) {
            const int col = col0 + wc * 32 + fc * 16 + l15;
            const float cbr = cbv[col]        + hbih[col]        + hbhh[col];
            const float cbz = cbv[col + 1024] + hbih[col + 1024] + hbhh[col + 1024];
            const float cbn = cbv[col + 2048] + hbih[col + 2048];
            const float bnh = hbhh[col + 2048];
            const float* car = Ca + (size_t)col * 8;
            const float* caz = Ca + (size_t)(col + 1024) * 8;
            const float* can = Ca + (size_t)(col + 2048) * 8;
            float4 r0 = LD4(car), r1 = LD4(car + 4);
            float4 z0 = LD4(caz), z1 = LD4(caz + 4);
            float4 n0 = LD4(can), n1 = LD4(can + 4);
            #pragma unroll
            for (int fr = 0; fr < 2; ++fr)
                #pragma unroll
                for (int j = 0; j < 4; ++j) {
                    const int n = row0 + wr * 32 + fr * 16 + lg * 4 + j;
                    const float m = mrow[n];
                    const float* ar = act + ((size_t)t * NB + n) * 8;
                    float4 a0 = LD4(ar), a1 = LD4(ar + 4);
                    const float dr = a0.x*r0.x + a0.y*r0.y + a0.z*r0.z + a0.w*r0.w
                                   + a1.x*r1.x + a1.y*r1.y + a1.z*r1.z + a1.w*r1.w;
                    const float dz = a0.x*z0.x + a0.y*z0.y + a0.z*z0.z + a0.w*z0.w
                                   + a1.x*z1.x + a1.y*z1.y + a1.z*z1.z + a1.w*z1.w;
                    const float dn = a0.x*n0.x + a0.y*n0.y + a0.z*n0.z + a0.w*n0.w
                                   + a1.x*n1.x + a1.y*n1.y + a1.z*n1.z + a1.w*n1.w;
                    const float rg = sigf(aR[fr][fc][j] + m * dr + cbr);
                    const float zg = sigf(aZ[fr][fc][j] + m * dz + cbz);
                    const float ng = tanhf(aNi[fr][fc][j] + m * dn + cbn
                                           + rg * (aNh[fr][fc][j] + bnh));
                    const float hm = hstF[(size_t)n * 1024 + col] * m;
                    const float o = (1.f - zg) * ng + zg * hm;
                    hstN[(size_t)n * 1024 + col] = o;
                    st_bf_swz(hbmN, n, col, o * mn[n]);
                }
        }
    } else if (b < 256) {   // ---- f-GRU: seg {f x fWhh}; gi from Gf ring
        const int i = b - 192;
        const int row0 = (i >> 4) * 64, col0 = (i & 15) * 64;
        f32x4 aR[2][2] = {}, aZ[2][2] = {}, aNi[2][2] = {}, aNh[2][2] = {};
        mm64g(tid, sA, sB,
              (const char*)fbm + (size_t)row0 * 2048, Wb + (size_t)(R_FWHH + col0) * 2048,
              nullptr, nullptr, nullptr, nullptr,
              1, 0b001, aR, aZ, aNi, aNh);
        const __bf16* gsl = Gfb + (size_t)(t & 7) * NB * THREEH;
        #pragma unroll
        for (int fc = 0; fc < 2; ++fc) {
            const int col = col0 + wc * 32 + fc * 16 + l15;
            const float br  = fbih[col] + fbhh[col];
            const float bz  = fbih[col + 1024] + fbhh[col + 1024];
            const float bni = fbih[col + 2048], bnh = fbhh[col + 2048];
            #pragma unroll
            for (int fr = 0; fr < 2; ++fr)
                #pragma unroll
                for (int j = 0; j < 4; ++j) {
                    const int n = row0 + wr * 32 + fr * 16 + lg * 4 + j;
                    const float gfr = (float)gsl[(size_t)n * THREEH + col];
                    const float gfz = (float)gsl[(size_t)n * THREEH + col + 1024];
                    const float gfn = (float)gsl[(size_t)n * THREEH + col + 2048];
                    const float rg = sigf(gfr + aR[fr][fc][j] + br);
                    const float zg = sigf(gfz + aZ[fr][fc][j] + bz);
                    const float ng = tanhf(gfn + bni + rg * (aNh[fr][fc][j] + bnh));
                    const float fm = fstF[(size_t)n * 1024 + col] * mrow[n];
                    const float o = (1.f - zg) * ng + zg * fm;
                    fstN[(size_t)n * 1024 + col] = o;
                    st_bf_swz(fbmN, n, col, o * mn[n]);
                }
        }
    } else if (b < 320) {   // ---- xq filler (slice t+LA)
        if (hasFiller) do_xq(t + LA, b - 256, tid, sA, sB, cbfB, Wb, act, qW, out);
    } else {                // ---- Gf filler (slice t+LA)
        if (hasFiller) do_gf(t + LA, b - 320, tid, sA, sB, cbfB, Wb, Gfb);
    }
}

// ---------------------------------------------------------------- final hxs
__global__ __launch_bounds__(256) void write_hxs_k(const float* __restrict__ fS,
                                                   const float* __restrict__ hS,
                                                   float* out) {
    const int i = blockIdx.x * 256 + threadIdx.x;
    const int n = i / THREEH;
    const int j = i - n * THREEH;
    float v;
    if (j < H)          v = fS[(size_t)n * H + j];
    else if (j < TWOH)  v = hS[(size_t)n * H + (j - H)];
    else                v = out[OFF_Q + ((size_t)(T - 1) * NB + n) * TWOH + (j - TWOH)];
    out[OFF_HX + i] = v;
}

// ---------------------------------------------------------------- launcher
extern "C" void kernel_launch(void* const* d_in, const int* in_sizes, int n_in,
                              void* d_out, int out_size, void* d_ws, size_t ws_size,
                              hipStream_t stream) {
    (void)in_sizes; (void)n_in; (void)out_size; (void)ws_size;

    const float* c     = (const float*)d_in[0];
    const float* hxs   = (const float*)d_in[1];
    const float* masks = (const float*)d_in[2];
    const float* act   = (const float*)d_in[3];
    const float* hWih  = (const float*)d_in[4];
    const float* hWhh  = (const float*)d_in[5];
    const float* hbih  = (const float*)d_in[6];
    const float* hbhh  = (const float*)d_in[7];
    const float* fWih  = (const float*)d_in[8];
    const float* fWhh  = (const float*)d_in[9];
    const float* fbih  = (const float*)d_in[10];
    const float* fbhh  = (const float*)d_in[11];
    const float* pW    = (const float*)d_in[12];
    const float* pb    = (const float*)d_in[13];
    const float* qW    = (const float*)d_in[14];
    const float* qb    = (const float*)d_in[15];

    float* out = (float*)d_out;
    char*  wsb = (char*)d_ws;

    __bf16* Wbf  = (__bf16*)(wsb);                               // 41.94 MB
    __bf16* cbf  = (__bf16*)(wsb + 41943040LL);                  // 33.55 MB
    float*  fst[2] = { (float*)(wsb + 75497472LL), (float*)(wsb + 76546048LL) };
    float*  hst[2] = { (float*)(wsb + 77594624LL), (float*)(wsb + 78643200LL) };
    __bf16* fbm[2] = { (__bf16*)(wsb + 79691776LL), (__bf16*)(wsb + 80216064LL) };
    __bf16* hbm[2] = { (__bf16*)(wsb + 80740352LL), (__bf16*)(wsb + 81264640LL) };
    __bf16* qmb[2] = { (__bf16*)(wsb + 81788928LL), (__bf16*)(wsb + 82313216LL) };
    __bf16* pWT    = (__bf16*)(wsb + 82837504LL);                // 4.19 MB
    __bf16* Chbuf  = (__bf16*)(wsb + 87031808LL);                // 6.29 MB
    __bf16* Cqbuf  = (__bf16*)(wsb + 93323264LL);                // 6.29 MB
    float*  Ca     = (float*)(wsb + 99614720LL);                 // 96 KB
    float*  cbv    = (float*)(wsb + 99713024LL);                 // 12 KB
    __bf16* Gfb    = (__bf16*)(wsb + 99725312LL);                // 12.58 MB -> ends ~112.3 MB
    const char* Wb   = (const char*)Wbf;
    const char* cbfB = (const char*)cbf;

    wcvt_k <<<dim3(10240), dim3(256), 0, stream>>>(pW, qW, fWih, fWhh, hWih, hWhh, Wbf);
    ccvt_k <<<dim3(8192),  dim3(256), 0, stream>>>(c, cbf);
    pwt_k  <<<dim3(32, 16), dim3(256), 0, stream>>>(pW, pWT);
    init2_k<<<dim3(384),   dim3(256), 0, stream>>>(hxs, masks, fst[0], hst[0],
                                                   fbm[0], hbm[0], qmb[0]);
    comp_k <<<dim3(768), dim3(256), 0, stream>>>(Wb, (const char*)pWT, Chbuf, Cqbuf);
    ca_k   <<<dim3(768), dim3(256), 0, stream>>>(hWih, pW, pb, Ca, cbv);
    pre_k  <<<dim3(LA * 160), dim3(256), 0, stream>>>(cbfB, Wb, act, qW, Gfb, out);

    for (int t = 0; t < T; ++t) {
        const int cur = t & 1, nxt = cur ^ 1;
        const int hasF = (t + LA < T) ? 1 : 0;
        step_k<<<dim3(hasF ? 416 : 256), dim3(256), 0, stream>>>(
            t, hasF, hbm[cur], qmb[cur], qmb[nxt], fbm[cur], cbfB,
            masks, act, pW, pb, qb, qW,
            Wb, (const char*)Chbuf, (const char*)Cqbuf, Ca, cbv,
            hst[cur], hst[nxt], hbm[nxt],
            fst[cur], fst[nxt], fbm[nxt],
            hbih, hbhh, fbih, fbhh, Gfb, out);
    }

    write_hxs_k<<<dim3(3072), dim3(256), 0, stream>>>(fst[0], hst[0], out);
}

// Round 8
// 2107.453 us; speedup vs baseline: 2.9599x; 2.9599x over previous
//
#include <hip/hip_runtime.h>
#include <math.h>

typedef __attribute__((ext_vector_type(8))) __bf16 bf16x8;
typedef __attribute__((ext_vector_type(4))) float f32x4;

constexpr int H = 1024, T = 64, NB = 256, TWOH = 2048, THREEH = 3072;
constexpr long long OFF_Q  = 33554432LL;
constexpr long long OFF_HX = 67108864LL;
constexpr int LA = 6;      // filler lookahead (ring of 8 slices)

// Wbf row offsets (rows of 1024 bf16, byte stride 2048)
constexpr int R_PWH = 0, R_PWQ = 2048, R_QWF = 4096, R_QWC = 6144,
              R_FWIH = 8192, R_FWHH = 11264, R_HWIH = 14336, R_HWHH = 17408;

#define LD4(p) (*reinterpret_cast<const float4*>(p))

__device__ __forceinline__ float sigf(float x) { return 1.0f / (1.0f + expf(-x)); }

__device__ __forceinline__ void gload16(const void* g, void* l) {
    __builtin_amdgcn_global_load_lds(
        (const __attribute__((address_space(1))) uint32_t*)g,
        (__attribute__((address_space(3))) uint32_t*)l, 16, 0, 0);
}

__device__ __forceinline__ void st_bf_swz(__bf16* base, int n, int k, float v) {
    base[(size_t)n * 1024 + (((k >> 3) ^ (n & 7)) << 3) + (k & 7)] = (__bf16)v;
}

#define FRAGOFF(rloc, gl) (((rloc) << 7) + ((((gl)) ^ ((rloc) & 7)) << 4))

// stage RT rows x 64 k from pre-swizzled global (row stride 2048B)
template<int RT>
__device__ __forceinline__ void stage_tile(const char* g, char* l, int kb, int tid) {
    #pragma unroll
    for (int i = 0; i < RT / 32; ++i) {
        const int L = i * 4096 + tid * 16;
        gload16(g + (size_t)(L >> 7) * 2048 + (size_t)kb * 128 + (L & 127), l + L);
    }
}

// ---------------------------------------------------------------- 64x128 GEMM core
// 3-deep pipeline: stage(k+2) in flight; vmcnt(12)/(6)/(0) ladder.
// sA: 3 x 8KB, sB: 3 x 16KB.
__device__ __forceinline__ void mm128(
    int tid, char* sA, char* sB,
    const char* A, const char* B, int nit,
    f32x4 (&acc)[2][4])
{
    const int lane = tid & 63, w = tid >> 6;
    const int l15 = lane & 15, lg = lane >> 4;
    const int wr = w >> 1, wc = w & 1;
    int aoff[2][2], boff[4][2];
    #pragma unroll
    for (int fr = 0; fr < 2; ++fr)
        #pragma unroll
        for (int kk = 0; kk < 2; ++kk)
            aoff[fr][kk] = FRAGOFF(wr * 32 + fr * 16 + l15, kk * 4 + lg);
    #pragma unroll
    for (int fc = 0; fc < 4; ++fc)
        #pragma unroll
        for (int kk = 0; kk < 2; ++kk)
            boff[fc][kk] = FRAGOFF(wc * 64 + fc * 16 + l15, kk * 4 + lg);

    stage_tile<64>(A, sA, 0, tid);
    stage_tile<128>(B, sB, 0, tid);
    if (nit > 1) {
        stage_tile<64>(A, sA + 8192, 1, tid);
        stage_tile<128>(B, sB + 16384, 1, tid);
    }
    for (int kb = 0; kb < nit; ++kb) {
        const int kn = kb + 2;
        if (kn < nit) {
            const int bo = kn % 3;
            stage_tile<64>(A, sA + bo * 8192, kn, tid);
            stage_tile<128>(B, sB + bo * 16384, kn, tid);
            asm volatile("s_waitcnt vmcnt(12)" ::: "memory");
        } else if (kb + 1 < nit) {
            asm volatile("s_waitcnt vmcnt(6)" ::: "memory");
        } else {
            asm volatile("s_waitcnt vmcnt(0)" ::: "memory");
        }
        __builtin_amdgcn_s_barrier();
        __builtin_amdgcn_sched_barrier(0);
        const int bc = kb % 3;
        char* Ab = sA + bc * 8192;
        char* Bb = sB + bc * 16384;
        bf16x8 af[2][2], bv[4][2];
        #pragma unroll
        for (int fr = 0; fr < 2; ++fr)
            #pragma unroll
            for (int kk = 0; kk < 2; ++kk)
                af[fr][kk] = *reinterpret_cast<const bf16x8*>(Ab + aoff[fr][kk]);
        #pragma unroll
        for (int fc = 0; fc < 4; ++fc)
            #pragma unroll
            for (int kk = 0; kk < 2; ++kk)
                bv[fc][kk] = *reinterpret_cast<const bf16x8*>(Bb + boff[fc][kk]);
        __builtin_amdgcn_s_setprio(1);
        #pragma unroll
        for (int kk = 0; kk < 2; ++kk)
            #pragma unroll
            for (int fr = 0; fr < 2; ++fr)
                #pragma unroll
                for (int fc = 0; fc < 4; ++fc)
                    acc[fr][fc] = __builtin_amdgcn_mfma_f32_16x16x32_bf16(
                        af[fr][kk], bv[fc][kk], acc[fr][fc], 0, 0, 0);
        __builtin_amdgcn_s_setprio(0);
        __builtin_amdgcn_s_barrier();
        __builtin_amdgcn_sched_barrier(0);
    }
}

// ---------------------------------------------------------------- 32x64 1-seg 3-gate core
// 2-deep (proven round 6). sA: 2 x 4KB, sB: 2 x 24KB.
__device__ __forceinline__ void mm32g1(
    int tid, char* sA, char* sB,
    const char* A, const char* Bg,
    f32x4 (&aR)[2], f32x4 (&aZ)[2], f32x4 (&aN)[2])
{
    const int lane = tid & 63, w = tid >> 6;
    const int l15 = lane & 15, lg = lane >> 4;
    const int wr = w >> 1, wc = w & 1;
    int aoff[2], boff[2][2];
    #pragma unroll
    for (int kk = 0; kk < 2; ++kk)
        aoff[kk] = FRAGOFF(wr * 16 + l15, kk * 4 + lg);
    #pragma unroll
    for (int fc = 0; fc < 2; ++fc)
        #pragma unroll
        for (int kk = 0; kk < 2; ++kk)
            boff[fc][kk] = FRAGOFF(wc * 32 + fc * 16 + l15, kk * 4 + lg);

    auto stg = [&](int buf, int kb) {
        stage_tile<32>(A, sA + buf * 4096, kb, tid);
        #pragma unroll
        for (int g = 0; g < 3; ++g)
            stage_tile<64>(Bg + (size_t)g * 2097152, sB + buf * 24576 + g * 8192, kb, tid);
    };
    stg(0, 0);
    for (int kb = 0; kb < 16; ++kb) {
        if (kb + 1 < 16) {
            stg((kb + 1) & 1, kb + 1);
            asm volatile("s_waitcnt vmcnt(7)" ::: "memory");
        } else {
            asm volatile("s_waitcnt vmcnt(0)" ::: "memory");
        }
        __builtin_amdgcn_s_barrier();
        __builtin_amdgcn_sched_barrier(0);
        char* Ab = sA + (kb & 1) * 4096;
        char* Bb = sB + (kb & 1) * 24576;
        bf16x8 af[2];
        #pragma unroll
        for (int kk = 0; kk < 2; ++kk)
            af[kk] = *reinterpret_cast<const bf16x8*>(Ab + aoff[kk]);
        bf16x8 bvr[2][2], bvz[2][2], bvn[2][2];
        #pragma unroll
        for (int fc = 0; fc < 2; ++fc)
            #pragma unroll
            for (int kk = 0; kk < 2; ++kk) {
                bvr[fc][kk] = *reinterpret_cast<const bf16x8*>(Bb + boff[fc][kk]);
                bvz[fc][kk] = *reinterpret_cast<const bf16x8*>(Bb + 8192 + boff[fc][kk]);
                bvn[fc][kk] = *reinterpret_cast<const bf16x8*>(Bb + 16384 + boff[fc][kk]);
            }
        __builtin_amdgcn_s_setprio(1);
        #pragma unroll
        for (int kk = 0; kk < 2; ++kk)
            #pragma unroll
            for (int fc = 0; fc < 2; ++fc) {
                aR[fc] = __builtin_amdgcn_mfma_f32_16x16x32_bf16(af[kk], bvr[fc][kk], aR[fc], 0, 0, 0);
                aZ[fc] = __builtin_amdgcn_mfma_f32_16x16x32_bf16(af[kk], bvz[fc][kk], aZ[fc], 0, 0, 0);
                aN[fc] = __builtin_amdgcn_mfma_f32_16x16x32_bf16(af[kk], bvn[fc][kk], aN[fc], 0, 0, 0);
            }
        __builtin_amdgcn_s_setprio(0);
        __builtin_amdgcn_s_barrier();
        __builtin_amdgcn_sched_barrier(0);
    }
}

// ---------------------------------------------------------------- shared bodies
// xq slice: out_q[slice] = c@qWc^T + a@qWa^T (raw, no bias/mask)
__device__ __forceinline__ void do_xq(int slice, int i, int tid, char* sA, char* sB,
    const char* cbfB, const char* Wb, const float* act, const float* qW, float* out)
{
    const int lane = tid & 63, w = tid >> 6;
    const int l15 = lane & 15, lg = lane >> 4;
    const int wr = w >> 1, wc = w & 1;
    const int row0 = (i >> 4) * 64, col0 = (i & 15) * 128;
    const size_t grow0 = (size_t)slice * NB + row0;
    f32x4 acc[2][4] = {};
    mm128(tid, sA, sB, cbfB + grow0 * 2048, Wb + (size_t)(R_QWC + col0) * 2048, 16, acc);
    #pragma unroll
    for (int fc = 0; fc < 4; ++fc) {
        const int gc = col0 + wc * 64 + fc * 16 + l15;
        const float* wp = qW + (size_t)gc * 2056 + 2048;
        float4 x0 = LD4(wp), x1 = LD4(wp + 4);
        #pragma unroll
        for (int fr = 0; fr < 2; ++fr)
            #pragma unroll
            for (int j = 0; j < 4; ++j) {
                const size_t n = grow0 + wr * 32 + fr * 16 + lg * 4 + j;
                const float* ar = act + n * 8;
                float4 a0 = LD4(ar), a1 = LD4(ar + 4);
                float dot = a0.x * x0.x + a0.y * x0.y + a0.z * x0.z + a0.w * x0.w
                          + a1.x * x1.x + a1.y * x1.y + a1.z * x1.z + a1.w * x1.w;
                out[OFF_Q + n * TWOH + gc] = acc[fr][fc][j] + dot;
            }
    }
}

// Gf slice: Gfb[slot] = c_t@fWih^T (bf16 ring)
__device__ __forceinline__ void do_gf(int slice, int i, int tid, char* sA, char* sB,
    const char* cbfB, const char* Wb, __bf16* Gfb)
{
    const int lane = tid & 63, w = tid >> 6;
    const int l15 = lane & 15, lg = lane >> 4;
    const int wr = w >> 1, wc = w & 1;
    const int row0 = (i / 24) * 64, col0 = (i % 24) * 128;
    f32x4 acc[2][4] = {};
    mm128(tid, sA, sB, cbfB + ((size_t)slice * NB + row0) * 2048,
          Wb + (size_t)(R_FWIH + col0) * 2048, 16, acc);
    __bf16* gdst = Gfb + (size_t)(slice & 7) * NB * THREEH;
    #pragma unroll
    for (int fc = 0; fc < 4; ++fc) {
        const int gc = col0 + wc * 64 + fc * 16 + l15;
        #pragma unroll
        for (int fr = 0; fr < 2; ++fr)
            #pragma unroll
            for (int j = 0; j < 4; ++j) {
                const int n = row0 + wr * 32 + fr * 16 + lg * 4 + j;
                gdst[(size_t)n * THREEH + gc] = (__bf16)acc[fr][fc][j];
            }
    }
}

// Pq partial for step tt: out_p[tt] = qmu(tt)@pWq^T + m*a@pWa^T + pb
// (qmu buffer is pre-masked; h-part added later by Pfinal)
__device__ __forceinline__ void do_pq(int tt, int i, int tid, char* sA, char* sB,
    const __bf16* qmu_t, const char* Wb, const float* masks, const float* act,
    const float* pW, const float* pb, float* out)
{
    const int lane = tid & 63, w = tid >> 6;
    const int l15 = lane & 15, lg = lane >> 4;
    const int wr = w >> 1, wc = w & 1;
    const int row0 = (i >> 4) * 64, col0 = (i & 15) * 128;
    f32x4 acc[2][4] = {};
    mm128(tid, sA, sB, (const char*)qmu_t + (size_t)row0 * 2048,
          Wb + (size_t)(R_PWQ + col0) * 2048, 16, acc);
    const float* mrow = masks + (size_t)tt * NB;
    float* ob = out + (size_t)tt * NB * TWOH;
    #pragma unroll
    for (int fc = 0; fc < 4; ++fc) {
        const int gc = col0 + wc * 64 + fc * 16 + l15;
        const float* wp = pW + (size_t)gc * 2056 + 2048;
        float4 x0 = LD4(wp), x1 = LD4(wp + 4);
        const float bb = pb[gc];
        #pragma unroll
        for (int fr = 0; fr < 2; ++fr)
            #pragma unroll
            for (int j = 0; j < 4; ++j) {
                const int n = row0 + wr * 32 + fr * 16 + lg * 4 + j;
                const float* ar = act + ((size_t)tt * NB + n) * 8;
                float4 a0 = LD4(ar), a1 = LD4(ar + 4);
                float dot = a0.x * x0.x + a0.y * x0.y + a0.z * x0.z + a0.w * x0.w
                          + a1.x * x1.x + a1.y * x1.y + a1.z * x1.z + a1.w * x1.w;
                ob[(size_t)n * TWOH + gc] = acc[fr][fc][j] + mrow[n] * dot + bb;
            }
    }
}

// ---------------------------------------------------------------- prepass kernels
__global__ __launch_bounds__(256) void wcvt_k(
    const float* __restrict__ pW, const float* __restrict__ qW,
    const float* __restrict__ fWih, const float* __restrict__ fWhh,
    const float* __restrict__ hWih, const float* __restrict__ hWhh,
    __bf16* __restrict__ Wbf)
{
    const long i = (long)blockIdx.x * 256 + threadIdx.x;
    const int row = (int)(i >> 7);
    const int G   = (int)i & 127;
    const float* src; int stride; int koff = 0; int r;
    if (row < 2048)       { src = pW;   stride = 2056; koff = 0;    r = row; }
    else if (row < 4096)  { src = pW;   stride = 2056; koff = 1024; r = row - 2048; }
    else if (row < 6144)  { src = qW;   stride = 2056; koff = 0;    r = row - 4096; }
    else if (row < 8192)  { src = qW;   stride = 2056; koff = 1024; r = row - 6144; }
    else if (row < 11264) { src = fWih; stride = 1024; r = row - 8192; }
    else if (row < 14336) { src = fWhh; stride = 1024; r = row - 11264; }
    else if (row < 17408) { src = hWih; stride = 1024; r = row - 14336; }
    else                  { src = hWhh; stride = 1024; r = row - 17408; }
    const float* p = src + (long)r * stride + koff + G * 8;
    float4 a = LD4(p), b = LD4(p + 4);
    bf16x8 v;
    v[0] = (__bf16)a.x; v[1] = (__bf16)a.y; v[2] = (__bf16)a.z; v[3] = (__bf16)a.w;
    v[4] = (__bf16)b.x; v[5] = (__bf16)b.y; v[6] = (__bf16)b.z; v[7] = (__bf16)b.w;
    *reinterpret_cast<bf16x8*>(Wbf + (size_t)row * 1024 + ((G ^ (row & 7)) << 3)) = v;
}

__global__ __launch_bounds__(256) void ccvt_k(const float* __restrict__ c,
                                              __bf16* __restrict__ cbf) {
    const long i = (long)blockIdx.x * 256 + threadIdx.x;
    const int row = (int)(i >> 7);
    const int G   = (int)i & 127;
    const float* p = c + (size_t)row * 1024 + G * 8;
    float4 a = LD4(p), b = LD4(p + 4);
    bf16x8 v;
    v[0] = (__bf16)a.x; v[1] = (__bf16)a.y; v[2] = (__bf16)a.z; v[3] = (__bf16)a.w;
    v[4] = (__bf16)b.x; v[5] = (__bf16)b.y; v[6] = (__bf16)b.z; v[7] = (__bf16)b.w;
    *reinterpret_cast<bf16x8*>(cbf + (size_t)row * 1024 + ((G ^ (row & 7)) << 3)) = v;
}

__global__ __launch_bounds__(256) void init2_k(
    const float* __restrict__ hxs, const float* __restrict__ masks,
    float* __restrict__ fst0, float* __restrict__ hst0,
    __bf16* __restrict__ fbm0, __bf16* __restrict__ hbm0, __bf16* __restrict__ qmub0)
{
    const int idx = blockIdx.x * 256 + threadIdx.x;
    const int arr = idx >> 15;
    const int g   = idx & 32767;
    const int n   = g >> 7;
    const int G   = g & 127;
    const float m0 = masks[n];
    const float* p = hxs + (size_t)n * THREEH + arr * 1024 + G * 8;
    float4 a = LD4(p), b = LD4(p + 4);
    __bf16* dstB = arr == 0 ? fbm0 : (arr == 1 ? hbm0 : qmub0);
    bf16x8 v;
    v[0] = (__bf16)(a.x * m0); v[1] = (__bf16)(a.y * m0);
    v[2] = (__bf16)(a.z * m0); v[3] = (__bf16)(a.w * m0);
    v[4] = (__bf16)(b.x * m0); v[5] = (__bf16)(b.y * m0);
    v[6] = (__bf16)(b.z * m0); v[7] = (__bf16)(b.w * m0);
    *reinterpret_cast<bf16x8*>(dstB + (size_t)n * 1024 + ((G ^ (n & 7)) << 3)) = v;
    if (arr < 2) {
        float* dstF = arr == 0 ? fst0 : hst0;
        *reinterpret_cast<float4*>(dstF + (size_t)n * 1024 + G * 8) = a;
        *reinterpret_cast<float4*>(dstF + (size_t)n * 1024 + G * 8 + 4) = b;
    }
}

// slices 0..LA-1 of xq and Gf, plus Pq(0)
__global__ __launch_bounds__(256) void pre_k(
    const char* __restrict__ cbfB, const char* __restrict__ Wb,
    const float* __restrict__ act, const float* __restrict__ qW,
    const __bf16* __restrict__ qmb0, const float* __restrict__ masks,
    const float* __restrict__ pW, const float* __restrict__ pb,
    __bf16* __restrict__ Gfb, float* __restrict__ out)
{
    __shared__ char smem[73728];
    if (blockIdx.x < LA * 160) {
        const int s = blockIdx.x / 160;
        const int i = blockIdx.x % 160;
        if (i < 64) do_xq(s, i, threadIdx.x, smem, smem + 24576, cbfB, Wb, act, qW, out);
        else        do_gf(s, i - 64, threadIdx.x, smem, smem + 24576, cbfB, Wb, Gfb);
    } else {
        do_pq(0, blockIdx.x - LA * 160, threadIdx.x, smem, smem + 24576,
              qmb0, Wb, masks, act, pW, pb, out);
    }
}

// ---------------------------------------------------------------- per-step K1
// [0,64) Pfinal | [64,128) Q | [128,224) h@hWhh->Shh | [224,352) f-GRU
__global__ __launch_bounds__(256) void k1_k(
    int t,
    const __bf16* __restrict__ hbm, const __bf16* __restrict__ fbm,
    __bf16* __restrict__ qmubN,
    const float* __restrict__ masks, const float* __restrict__ act,
    const float* __restrict__ qb, const float* __restrict__ qW,
    const char* __restrict__ Wb,
    __bf16* __restrict__ pmub, float* __restrict__ Shh,
    const __bf16* __restrict__ Gfb,
    const float* __restrict__ fbih, const float* __restrict__ fbhh,
    const float* __restrict__ fstF, float* __restrict__ fstN, __bf16* __restrict__ fbmN,
    float* __restrict__ out)
{
    __shared__ char smem[73728];
    char* sA = smem;
    char* sB = smem + 24576;
    const int tid = threadIdx.x;
    const int lane = tid & 63, w = tid >> 6;
    const int l15 = lane & 15, lg = lane >> 4;
    const int wr = w >> 1, wc = w & 1;
    const float* mrow = masks + (size_t)t * NB;
    const float* mn   = masks + (size_t)(t + 1 < T ? t + 1 : t) * NB;
    int b = blockIdx.x;

    if (b < 64) {           // ---- Pfinal: out[t] += h@pWh (operand pre-masked)
        const int row0 = (b >> 4) * 64, col0 = (b & 15) * 128;
        f32x4 acc[2][4] = {};
        mm128(tid, sA, sB,
              (const char*)hbm + (size_t)row0 * 2048,
              Wb + (size_t)(R_PWH + col0) * 2048, 16, acc);
        float* ob = out + (size_t)t * NB * TWOH;
        #pragma unroll
        for (int fc = 0; fc < 4; ++fc) {
            const int gc = col0 + wc * 64 + fc * 16 + l15;
            #pragma unroll
            for (int fr = 0; fr < 2; ++fr)
                #pragma unroll
                for (int j = 0; j < 4; ++j) {
                    const int n = row0 + wr * 32 + fr * 16 + lg * 4 + j;
                    const float v = ob[(size_t)n * TWOH + gc] + acc[fr][fc][j];
                    ob[(size_t)n * TWOH + gc] = v;
                    if (gc < 1024) st_bf_swz(pmub, n, gc, v);
                }
        }
    } else if (b < 128) {   // ---- Q
        b -= 64;
        const int row0 = (b >> 4) * 64, col0 = (b & 15) * 128;
        f32x4 acc[2][4] = {};
        mm128(tid, sA, sB,
              (const char*)fbm + (size_t)row0 * 2048,
              Wb + (size_t)(R_QWF + col0) * 2048, 16, acc);
        float* ob = out + OFF_Q + (size_t)t * NB * TWOH;
        #pragma unroll
        for (int fc = 0; fc < 4; ++fc) {
            const int gc = col0 + wc * 64 + fc * 16 + l15;
            const float bb = qb[gc];
            #pragma unroll
            for (int fr = 0; fr < 2; ++fr)
                #pragma unroll
                for (int j = 0; j < 4; ++j) {
                    const int n = row0 + wr * 32 + fr * 16 + lg * 4 + j;
                    const float xq = ob[(size_t)n * TWOH + gc];
                    float v = acc[fr][fc][j] + mrow[n] * xq + bb;
                    ob[(size_t)n * TWOH + gc] = v;
                    if (gc < 1024) st_bf_swz(qmubN, n, gc, v * mn[n]);
                }
        }
    } else if (b < 224) {   // ---- h@hWhh -> Shh
        const int i = b - 128;
        const int row0 = (i / 24) * 64, col0 = (i % 24) * 128;
        f32x4 acc[2][4] = {};
        mm128(tid, sA, sB,
              (const char*)hbm + (size_t)row0 * 2048,
              Wb + (size_t)(R_HWHH + col0) * 2048, 16, acc);
        #pragma unroll
        for (int fc = 0; fc < 4; ++fc) {
            const int gc = col0 + wc * 64 + fc * 16 + l15;
            #pragma unroll
            for (int fr = 0; fr < 2; ++fr)
                #pragma unroll
                for (int j = 0; j < 4; ++j) {
                    const int n = row0 + wr * 32 + fr * 16 + lg * 4 + j;
                    Shh[(size_t)n * THREEH + gc] = acc[fr][fc][j];
                }
        }
    } else {                // ---- f-GRU: f@fWhh + Gf ring + combine
        const int i = b - 224;
        const int row0 = (i >> 4) * 32, col0 = (i & 15) * 64;
        f32x4 aR[2] = {}, aZ[2] = {}, aN[2] = {};
        mm32g1(tid, sA, sB,
               (const char*)fbm + (size_t)row0 * 2048,
               Wb + (size_t)(R_FWHH + col0) * 2048, aR, aZ, aN);
        const __bf16* gsl = Gfb + (size_t)(t & 7) * NB * THREEH;
        #pragma unroll
        for (int fc = 0; fc < 2; ++fc) {
            const int col = col0 + wc * 32 + fc * 16 + l15;
            const float br  = fbih[col] + fbhh[col];
            const float bz  = fbih[col + 1024] + fbhh[col + 1024];
            const float bni = fbih[col + 2048], bnh = fbhh[col + 2048];
            #pragma unroll
            for (int j = 0; j < 4; ++j) {
                const int n = row0 + wr * 16 + lg * 4 + j;
                const float gfr = (float)gsl[(size_t)n * THREEH + col];
                const float gfz = (float)gsl[(size_t)n * THREEH + col + 1024];
                const float gfn = (float)gsl[(size_t)n * THREEH + col + 2048];
                const float rg = sigf(gfr + aR[fc][j] + br);
                const float zg = sigf(gfz + aZ[fc][j] + bz);
                const float ng = tanhf(gfn + bni + rg * (aN[fc][j] + bnh));
                const float fm = fstF[(size_t)n * 1024 + col] * mrow[n];
                const float o = (1.f - zg) * ng + zg * fm;
                fstN[(size_t)n * 1024 + col] = o;
                st_bf_swz(fbmN, n, col, o * mn[n]);
            }
        }
    }
}

// ---------------------------------------------------------------- per-step K2
// [0,128) h-GRU | [128,192) Pq(t+1) | [192,256) xq(t+LA) | [256,352) Gf(t+LA)
__global__ __launch_bounds__(256) void k2_k(
    int t,
    const __bf16* __restrict__ pmub, const __bf16* __restrict__ qmubN,
    const char* __restrict__ cbfB,
    const float* __restrict__ Shh,
    const float* __restrict__ hstF, float* __restrict__ hstN, __bf16* __restrict__ hbmN,
    const char* __restrict__ Wb,
    const float* __restrict__ hbih, const float* __restrict__ hbhh,
    const float* __restrict__ masks, const float* __restrict__ act,
    const float* __restrict__ pW, const float* __restrict__ pb,
    const float* __restrict__ qW,
    __bf16* __restrict__ Gfb, float* __restrict__ out)
{
    __shared__ char smem[73728];
    char* sA = smem;
    char* sB = smem + 24576;
    const int tid = threadIdx.x;
    const int lane = tid & 63, w = tid >> 6;
    const int l15 = lane & 15, lg = lane >> 4;
    const int wr = w >> 1, wc = w & 1;
    const float* mrow = masks + (size_t)t * NB;
    const float* mn   = masks + (size_t)(t + 1 < T ? t + 1 : t) * NB;
    const int b = blockIdx.x;

    if (b < 128) {          // ---- h-GRU: pmu@hWih + Shh + combine
        const int row0 = (b >> 4) * 32, col0 = (b & 15) * 64;
        f32x4 aR[2] = {}, aZ[2] = {}, aN[2] = {};
        mm32g1(tid, sA, sB,
               (const char*)pmub + (size_t)row0 * 2048,
               Wb + (size_t)(R_HWIH + col0) * 2048, aR, aZ, aN);
        #pragma unroll
        for (int fc = 0; fc < 2; ++fc) {
            const int col = col0 + wc * 32 + fc * 16 + l15;
            const float bri = hbih[col],        brh = hbhh[col];
            const float bzi = hbih[col + 1024], bzh = hbhh[col + 1024];
            const float bni = hbih[col + 2048], bnh = hbhh[col + 2048];
            #pragma unroll
            for (int j = 0; j < 4; ++j) {
                const int n = row0 + wr * 16 + lg * 4 + j;
                const float ghr = Shh[(size_t)n * THREEH + col];
                const float ghz = Shh[(size_t)n * THREEH + col + 1024];
                const float ghn = Shh[(size_t)n * THREEH + col + 2048];
                const float rg = sigf(aR[fc][j] + bri + ghr + brh);
                const float zg = sigf(aZ[fc][j] + bzi + ghz + bzh);
                const float ng = tanhf(aN[fc][j] + bni + rg * (ghn + bnh));
                const float hm = hstF[(size_t)n * 1024 + col] * mrow[n];
                const float o = (1.f - zg) * ng + zg * hm;
                hstN[(size_t)n * 1024 + col] = o;
                st_bf_swz(hbmN, n, col, o * mn[n]);
            }
        }
    } else if (b < 192) {   // ---- Pq partial for step t+1
        if (t + 1 < T)
            do_pq(t + 1, b - 128, tid, sA, sB, qmubN, Wb, masks, act, pW, pb, out);
    } else if (b < 256) {   // ---- xq filler (slice t+LA)
        if (t + LA < T)
            do_xq(t + LA, b - 192, tid, sA, sB, cbfB, Wb, act, qW, out);
    } else {                // ---- Gf filler (slice t+LA)
        if (t + LA < T)
            do_gf(t + LA, b - 256, tid, sA, sB, cbfB, Wb, Gfb);
    }
}

// ---------------------------------------------------------------- final hxs
__global__ __launch_bounds__(256) void write_hxs_k(const float* __restrict__ fS,
                                                   const float* __restrict__ hS,
                                                   float* out) {
    const int i = blockIdx.x * 256 + threadIdx.x;
    const int n = i / THREEH;
    const int j = i - n * THREEH;
    float v;
    if (j < H)          v = fS[(size_t)n * H + j];
    else if (j < TWOH)  v = hS[(size_t)n * H + (j - H)];
    else                v = out[OFF_Q + ((size_t)(T - 1) * NB + n) * TWOH + (j - TWOH)];
    out[OFF_HX + i] = v;
}

// ---------------------------------------------------------------- launcher
extern "C" void kernel_launch(void* const* d_in, const int* in_sizes, int n_in,
                              void* d_out, int out_size, void* d_ws, size_t ws_size,
                              hipStream_t stream) {
    (void)in_sizes; (void)n_in; (void)out_size; (void)ws_size;

    const float* c     = (const float*)d_in[0];
    const float* hxs   = (const float*)d_in[1];
    const float* masks = (const float*)d_in[2];
    const float* act   = (const float*)d_in[3];
    const float* hWih  = (const float*)d_in[4];
    const float* hWhh  = (const float*)d_in[5];
    const float* hbih  = (const float*)d_in[6];
    const float* hbhh  = (const float*)d_in[7];
    const float* fWih  = (const float*)d_in[8];
    const float* fWhh  = (const float*)d_in[9];
    const float* fbih  = (const float*)d_in[10];
    const float* fbhh  = (const float*)d_in[11];
    const float* pW    = (const float*)d_in[12];
    const float* pb    = (const float*)d_in[13];
    const float* qW    = (const float*)d_in[14];
    const float* qb    = (const float*)d_in[15];

    float* out = (float*)d_out;
    char*  wsb = (char*)d_ws;

    __bf16* Wbf  = (__bf16*)(wsb);                               // 41.94 MB
    __bf16* cbf  = (__bf16*)(wsb + 41943040LL);                  // 33.55 MB
    float*  fst[2] = { (float*)(wsb + 75497472LL), (float*)(wsb + 76546048LL) };
    float*  hst[2] = { (float*)(wsb + 77594624LL), (float*)(wsb + 78643200LL) };
    __bf16* fbm[2] = { (__bf16*)(wsb + 79691776LL), (__bf16*)(wsb + 80216064LL) };
    __bf16* hbm[2] = { (__bf16*)(wsb + 80740352LL), (__bf16*)(wsb + 81264640LL) };
    __bf16* qmb[2] = { (__bf16*)(wsb + 81788928LL), (__bf16*)(wsb + 82313216LL) };
    __bf16* pmub   = (__bf16*)(wsb + 82837504LL);                // 0.52 MB
    float*  Shh    = (float*)(wsb + 83361792LL);                 // 3.15 MB
    __bf16* Gfb    = (__bf16*)(wsb + 86507520LL);                // 8 x 1.57 MB -> ends ~99.1 MB
    const char* Wb   = (const char*)Wbf;
    const char* cbfB = (const char*)cbf;

    wcvt_k <<<dim3(10240), dim3(256), 0, stream>>>(pW, qW, fWih, fWhh, hWih, hWhh, Wbf);
    ccvt_k <<<dim3(8192),  dim3(256), 0, stream>>>(c, cbf);
    init2_k<<<dim3(384),   dim3(256), 0, stream>>>(hxs, masks, fst[0], hst[0],
                                                   fbm[0], hbm[0], qmb[0]);
    pre_k  <<<dim3(LA * 160 + 64), dim3(256), 0, stream>>>(
        cbfB, Wb, act, qW, qmb[0], masks, pW, pb, Gfb, out);

    for (int t = 0; t < T; ++t) {
        const int cur = t & 1, nxt = cur ^ 1;
        k1_k<<<dim3(352), dim3(256), 0, stream>>>(
            t, hbm[cur], fbm[cur], qmb[nxt],
            masks, act, qb, qW, Wb, pmub, Shh, Gfb,
            fbih, fbhh, fst[cur], fst[nxt], fbm[nxt], out);
        k2_k<<<dim3(352), dim3(256), 0, stream>>>(
            t, pmub, qmb[nxt], cbfB, Shh,
            hst[cur], hst[nxt], hbm[nxt],
            Wb, hbih, hbhh, masks, act, pW, pb, qW, Gfb, out);
    }

    write_hxs_k<<<dim3(3072), dim3(256), 0, stream>>>(fst[0], hst[0], out);
}